// Round 1
// baseline (330.572 us; speedup 1.0000x reference)
//
#include <hip/hip_runtime.h>
#include <hip/hip_bf16.h>

#define NN 2560        // nodes
#define NE 163840      // edges
#define NH 4           // heads
#define NC 128         // channels per head
#define NF 512         // NH*NC
#define OUTE 40

// ---------------- kernel 1: edge weights + degree count -------------------
__global__ void k_edge_init(const int* __restrict__ ei, const float* __restrict__ pos,
                            float* __restrict__ ew, int* __restrict__ deg) {
    int e = blockIdx.x * 256 + threadIdx.x;
    if (e >= NE) return;
    int s = ei[e], d = ei[NE + e];
    float dx = pos[2 * s] - pos[2 * d];
    float dy = pos[2 * s + 1] - pos[2 * d + 1];
    ew[e] = 1.0f / (sqrtf(dx * dx + dy * dy) + 1e-6f);
    atomicAdd(&deg[d], 1);
}

// ---------------- kernel 2: exclusive scan of deg -> offs (single block) ---
__global__ void k_scan(const int* __restrict__ deg, int* __restrict__ offs) {
    __shared__ int cs[256];
    int t = threadIdx.x;
    int base = t * 10;
    int local[10];
    int s = 0;
#pragma unroll
    for (int i = 0; i < 10; i++) { local[i] = deg[base + i]; s += local[i]; }
    cs[t] = s;
    __syncthreads();
    // Hillis-Steele inclusive scan over 256 chunk sums
    for (int off = 1; off < 256; off <<= 1) {
        int v = (t >= off) ? cs[t - off] : 0;
        __syncthreads();
        cs[t] += v;
        __syncthreads();
    }
    int excl = (t == 0) ? 0 : cs[t - 1];
#pragma unroll
    for (int i = 0; i < 10; i++) { offs[base + i] = excl; excl += local[i]; }
    if (t == 255) offs[NN] = excl;
}

// ---------------- kernel 3: CSR fill --------------------------------------
__global__ void k_csr_fill(const int* __restrict__ ei, const int* __restrict__ offs,
                           int* __restrict__ cursor, int* __restrict__ csr) {
    int e = blockIdx.x * 256 + threadIdx.x;
    if (e >= NE) return;
    int d = ei[NE + e];
    int p = atomicAdd(&cursor[d], 1);
    csr[offs[d] + p] = e;
}

// ---------------- kernel 4: per-head edge-attention scalar ----------------
// dote[h] = sum_c We[h*128+c] * att_e[h*128+c]
__global__ void k_dote(const float* __restrict__ We, const float* __restrict__ ae,
                       float* __restrict__ dote) {
    int t = threadIdx.x;
    int w = t >> 6, l = t & 63;
    float p = We[w * 128 + l] * ae[w * 128 + l] + We[w * 128 + 64 + l] * ae[w * 128 + 64 + l];
#pragma unroll
    for (int o = 32; o > 0; o >>= 1) p += __shfl_down(p, o);
    if (l == 0) dote[w] = p;
}

// ---------------- kernel 5: GEMM1 h = x @ W1 (K=32) -----------------------
__global__ void k_gemm1(const float* __restrict__ x, const float* __restrict__ W1,
                        float* __restrict__ h) {
    int idx = blockIdx.x * 256 + threadIdx.x;   // n*512 + j
    int n = idx >> 9, j = idx & 511;
    const float* xr = x + n * 32;
    float acc = 0.f;
#pragma unroll
    for (int k = 0; k < 32; k++) acc += xr[k] * W1[k * 512 + j];
    h[idx] = acc;
}

// ---------------- kernel 6: node attention scalars a_s, a_d ---------------
// one wave per (node, head)
__global__ void k_node_att(const float* __restrict__ h, const float* __restrict__ atts,
                           const float* __restrict__ attd, float* __restrict__ as_,
                           float* __restrict__ ad_) {
    int b = blockIdx.x;
    int n = b >> 2, hd = b & 3;
    int l = threadIdx.x;
    const float* hr = h + n * NF + hd * NC;
    const float* sp = atts + hd * NC;
    const float* dp = attd + hd * NC;
    float ps = hr[l] * sp[l] + hr[l + 64] * sp[l + 64];
    float pd = hr[l] * dp[l] + hr[l + 64] * dp[l + 64];
#pragma unroll
    for (int o = 32; o > 0; o >>= 1) { ps += __shfl_down(ps, o); pd += __shfl_down(pd, o); }
    if (l == 0) { as_[n * 4 + hd] = ps; ad_[n * 4 + hd] = pd; }
}

// ---------------- kernel 7: per-edge pre-softmax logits -------------------
__global__ void k_alpha(const int* __restrict__ ei, const float* __restrict__ ew,
                        const float4* __restrict__ as4, const float4* __restrict__ ad4,
                        const float* __restrict__ dote, float4* __restrict__ alpha4) {
    int e = blockIdx.x * 256 + threadIdx.x;
    if (e >= NE) return;
    int s = ei[e], d = ei[NE + e];
    float w = ew[e];
    float4 a = as4[s], b = ad4[d];
    float4 r;
    float v;
    v = a.x + b.x + w * dote[0]; r.x = v > 0.f ? v : 0.2f * v;
    v = a.y + b.y + w * dote[1]; r.y = v > 0.f ? v : 0.2f * v;
    v = a.z + b.z + w * dote[2]; r.z = v > 0.f ? v : 0.2f * v;
    v = a.w + b.w + w * dote[3]; r.w = v > 0.f ? v : 0.2f * v;
    alpha4[e] = r;
}

// ---------------- kernel 8: segment softmax (one wave per dst node) -------
__global__ void k_softmax(const int* __restrict__ offs, const int* __restrict__ csr,
                          float4* __restrict__ alpha4) {
    int n = blockIdx.x, l = threadIdx.x;
    int beg = offs[n], end = offs[n + 1];
    float4 m = make_float4(-1e30f, -1e30f, -1e30f, -1e30f);
    for (int i = beg + l; i < end; i += 64) {
        float4 a = alpha4[csr[i]];
        m.x = fmaxf(m.x, a.x); m.y = fmaxf(m.y, a.y);
        m.z = fmaxf(m.z, a.z); m.w = fmaxf(m.w, a.w);
    }
#pragma unroll
    for (int o = 32; o > 0; o >>= 1) {
        m.x = fmaxf(m.x, __shfl_xor(m.x, o)); m.y = fmaxf(m.y, __shfl_xor(m.y, o));
        m.z = fmaxf(m.z, __shfl_xor(m.z, o)); m.w = fmaxf(m.w, __shfl_xor(m.w, o));
    }
    float4 ss = make_float4(0.f, 0.f, 0.f, 0.f);
    for (int i = beg + l; i < end; i += 64) {
        int e = csr[i];
        float4 a = alpha4[e];
        a.x = __expf(a.x - m.x); a.y = __expf(a.y - m.y);
        a.z = __expf(a.z - m.z); a.w = __expf(a.w - m.w);
        alpha4[e] = a;
        ss.x += a.x; ss.y += a.y; ss.z += a.z; ss.w += a.w;
    }
#pragma unroll
    for (int o = 32; o > 0; o >>= 1) {
        ss.x += __shfl_xor(ss.x, o); ss.y += __shfl_xor(ss.y, o);
        ss.z += __shfl_xor(ss.z, o); ss.w += __shfl_xor(ss.w, o);
    }
    float4 inv;
    inv.x = 1.f / (ss.x + 1e-16f); inv.y = 1.f / (ss.y + 1e-16f);
    inv.z = 1.f / (ss.z + 1e-16f); inv.w = 1.f / (ss.w + 1e-16f);
    for (int i = beg + l; i < end; i += 64) {
        int e = csr[i];
        float4 a = alpha4[e];
        a.x *= inv.x; a.y *= inv.y; a.z *= inv.z; a.w *= inv.w;
        alpha4[e] = a;
    }
}

// ---------------- kernel 9: weighted aggregation (block per node) ---------
#define AGG_CHUNK 64
__global__ __launch_bounds__(256) void k_agg(const int* __restrict__ offs,
        const int* __restrict__ csr, const int* __restrict__ ei,
        const float* __restrict__ alpha, const float* __restrict__ h,
        const float* __restrict__ bias, float* __restrict__ out) {
    __shared__ int s_src[AGG_CHUNK];
    __shared__ float s_alpha[AGG_CHUNK][4];
    int n = blockIdx.x, t = threadIdx.x;
    int beg = offs[n], end = offs[n + 1];
    float acc0 = 0.f, acc1 = 0.f;
    int h0 = t >> 7;       // head of channel t       (0 or 1)
    int h1 = 2 + h0;       // head of channel t+256   (2 or 3)
    for (int base = beg; base < end; base += AGG_CHUNK) {
        int cnt = min(AGG_CHUNK, end - base);
        __syncthreads();
        if (t < cnt) s_src[t] = ei[csr[base + t]];
        int eidx = t >> 2, hh = t & 3;
        if (eidx < cnt) {
            int e = csr[base + eidx];
            s_alpha[eidx][hh] = alpha[e * 4 + hh];
        }
        __syncthreads();
        for (int i = 0; i < cnt; i++) {
            const float* hr = h + s_src[i] * NF;
            acc0 += s_alpha[i][h0] * hr[t];
            acc1 += s_alpha[i][h1] * hr[256 + t];
        }
    }
    out[n * NF + t] = acc0 + bias[t];
    out[n * NF + 256 + t] = acc1 + bias[256 + t];
}

// ---------------- kernel 10: BN stats (sum, sumsq per column) -------------
__global__ void k_bnstats(const float* __restrict__ x, float* __restrict__ stats) {
    int t = threadIdx.x;
    int r0 = blockIdx.x * 128;
    float s = 0.f, s2 = 0.f;
    for (int r = r0; r < r0 + 128; r++) {
        float v = x[r * NF + t];
        s += v; s2 += v * v;
    }
    atomicAdd(&stats[t], s);
    atomicAdd(&stats[NF + t], s2);
}

// ---------------- kernel 11: BN apply + relu ------------------------------
__global__ void k_bnapply(const float* __restrict__ x, const float* __restrict__ stats,
                          const float* __restrict__ g, const float* __restrict__ b,
                          float* __restrict__ y) {
    int idx = blockIdx.x * 256 + threadIdx.x;
    int j = idx & 511;
    const float invn = 1.0f / (float)NN;
    float mu = stats[j] * invn;
    float var = stats[NF + j] * invn - mu * mu;
    float v = (x[idx] - mu) * rsqrtf(var + 1e-5f) * g[j] + b[j];
    y[idx] = fmaxf(v, 0.f);
}

// ---------------- kernel 12: GEMM2 C[2560,512] = A[2560,512]@B[512,512] ---
__global__ __launch_bounds__(256) void k_gemm2(const float* __restrict__ A,
        const float* __restrict__ B, float* __restrict__ C) {
    __shared__ float As[16][68];   // [k][m], padded stride 68 to spread banks
    __shared__ float Bs[16][64];   // [k][n]
    int tid = threadIdx.x;
    int rowBase = blockIdx.y * 64, colBase = blockIdx.x * 64;
    int tx = tid & 15, ty = tid >> 4;
    int ar = tid >> 2;            // 0..63
    int ak = (tid & 3) * 4;       // 0,4,8,12
    int bk = tid >> 4;            // 0..15
    int bc = (tid & 15) * 4;      // 0..60
    float acc[4][4] = {};
    for (int k0 = 0; k0 < 512; k0 += 16) {
        __syncthreads();
        float4 a4 = *(const float4*)(A + (rowBase + ar) * 512 + k0 + ak);
        float4 b4 = *(const float4*)(B + (k0 + bk) * 512 + colBase + bc);
        As[ak + 0][ar] = a4.x; As[ak + 1][ar] = a4.y;
        As[ak + 2][ar] = a4.z; As[ak + 3][ar] = a4.w;
        *(float4*)(&Bs[bk][bc]) = b4;
        __syncthreads();
#pragma unroll
        for (int k = 0; k < 16; k++) {
            float4 ra = *(const float4*)(&As[k][ty * 4]);
            float4 rb = *(const float4*)(&Bs[k][tx * 4]);
            acc[0][0] += ra.x * rb.x; acc[0][1] += ra.x * rb.y; acc[0][2] += ra.x * rb.z; acc[0][3] += ra.x * rb.w;
            acc[1][0] += ra.y * rb.x; acc[1][1] += ra.y * rb.y; acc[1][2] += ra.y * rb.z; acc[1][3] += ra.y * rb.w;
            acc[2][0] += ra.z * rb.x; acc[2][1] += ra.z * rb.y; acc[2][2] += ra.z * rb.z; acc[2][3] += ra.z * rb.w;
            acc[3][0] += ra.w * rb.x; acc[3][1] += ra.w * rb.y; acc[3][2] += ra.w * rb.z; acc[3][3] += ra.w * rb.w;
        }
    }
#pragma unroll
    for (int i = 0; i < 4; i++) {
        float4 v = make_float4(acc[i][0], acc[i][1], acc[i][2], acc[i][3]);
        *(float4*)(C + (rowBase + ty * 4 + i) * 512 + colBase + tx * 4) = v;
    }
}

// ---------------- kernel 13: FC + mask + adjacency ------------------------
__global__ void k_fc(const float* __restrict__ e2, const float* __restrict__ Wfc,
                     const float* __restrict__ bfc, const int* __restrict__ mask,
                     const float* __restrict__ adj, float* __restrict__ out) {
    int idx = blockIdx.x * 256 + threadIdx.x;   // n*40 + j
    if (idx >= NN * OUTE) return;
    int n = idx / OUTE, j = idx - n * OUTE;
    const float* er = e2 + n * NF;
    float acc = 0.f;
    for (int k = 0; k < NF; k++) acc += er[k] * Wfc[k * OUTE + j];
    float r = mask[n] ? (acc + bfc[j]) : 0.f;
    out[idx] = r + adj[idx];
}

// ---------------- host side ----------------------------------------------
extern "C" void kernel_launch(void* const* d_in, const int* in_sizes, int n_in,
                              void* d_out, int out_size, void* d_ws, size_t ws_size,
                              hipStream_t stream) {
    const float* x       = (const float*)d_in[0];
    const int*   ei      = (const int*)d_in[1];
    const float* pos     = (const float*)d_in[2];
    const int*   mask    = (const int*)d_in[3];
    const float* adj     = (const float*)d_in[4];
    const float* W1      = (const float*)d_in[5];
    const float* atts1   = (const float*)d_in[6];
    const float* attd1   = (const float*)d_in[7];
    const float* We1     = (const float*)d_in[8];
    const float* atte1   = (const float*)d_in[9];
    const float* bias1   = (const float*)d_in[10];
    const float* g1      = (const float*)d_in[11];
    const float* be1     = (const float*)d_in[12];
    const float* W2      = (const float*)d_in[13];
    const float* atts2   = (const float*)d_in[14];
    const float* attd2   = (const float*)d_in[15];
    const float* We2     = (const float*)d_in[16];
    const float* atte2   = (const float*)d_in[17];
    const float* bias2   = (const float*)d_in[18];
    const float* g2      = (const float*)d_in[19];
    const float* be2     = (const float*)d_in[20];
    const float* Wfc     = (const float*)d_in[21];
    const float* bfc     = (const float*)d_in[22];
    float* out = (float*)d_out;

    // workspace layout (element offsets, all 16-element aligned where needed)
    char* ws = (char*)d_ws;
    int*   deg    = (int*)(ws);                         // 2560
    int*   cursor = (int*)(ws + 2560 * 4);              // 2560
    float* stats  = (float*)(ws + 5120 * 4);            // 2048 (stats1: 1024, stats2: 1024)
    // zero region = first 7168 elements
    int*   offs   = (int*)(ws + 7168 * 4);              // 2561 -> pad to 2576
    float* dote   = (float*)(ws + 9744 * 4);            // 8 -> pad 16
    int*   csr    = (int*)(ws + 9760 * 4);              // 163840
    float* ew     = (float*)(ws + 173600 * 4);          // 163840
    float* as_    = (float*)(ws + 337440 * 4);          // 10240
    float* ad_    = (float*)(ws + 347680 * 4);          // 10240
    float* alpha  = (float*)(ws + 357920 * 4);          // 655360
    float* t0     = (float*)(ws + 1013280 * 4);         // 1310720
    float* t1     = (float*)(ws + 2324000 * 4);         // 1310720
    // total 3634720 elements = ~14.5 MB

    hipMemsetAsync(d_ws, 0, 7168 * 4, stream);

    // graph structure (recomputed every launch; inputs restored each call)
    k_edge_init<<<NE / 256, 256, 0, stream>>>(ei, pos, ew, deg);
    k_scan<<<1, 256, 0, stream>>>(deg, offs);
    k_csr_fill<<<NE / 256, 256, 0, stream>>>(ei, offs, cursor, csr);
    k_dote<<<1, 256, 0, stream>>>(We1, atte1, dote);
    k_dote<<<1, 256, 0, stream>>>(We2, atte2, dote + 4);

    // ---- layer 1 ----
    k_gemm1<<<NN * NF / 256, 256, 0, stream>>>(x, W1, t0);
    k_node_att<<<NN * NH, 64, 0, stream>>>(t0, atts1, attd1, as_, ad_);
    k_alpha<<<NE / 256, 256, 0, stream>>>(ei, ew, (const float4*)as_, (const float4*)ad_, dote, (float4*)alpha);
    k_softmax<<<NN, 64, 0, stream>>>(offs, csr, (float4*)alpha);
    k_agg<<<NN, 256, 0, stream>>>(offs, csr, ei, alpha, t0, bias1, t1);
    k_bnstats<<<NN / 128, 512, 0, stream>>>(t1, stats);
    k_bnapply<<<NN * NF / 256, 256, 0, stream>>>(t1, stats, g1, be1, t0);

    // ---- layer 2 ----
    dim3 g2grid(512 / 64, NN / 64);
    k_gemm2<<<g2grid, 256, 0, stream>>>(t0, W2, t1);
    k_node_att<<<NN * NH, 64, 0, stream>>>(t1, atts2, attd2, as_, ad_);
    k_alpha<<<NE / 256, 256, 0, stream>>>(ei, ew, (const float4*)as_, (const float4*)ad_, dote + 4, (float4*)alpha);
    k_softmax<<<NN, 64, 0, stream>>>(offs, csr, (float4*)alpha);
    k_agg<<<NN, 256, 0, stream>>>(offs, csr, ei, alpha, t1, bias2, t0);
    k_bnstats<<<NN / 128, 512, 0, stream>>>(t0, stats + 1024);
    k_bnapply<<<NN * NF / 256, 256, 0, stream>>>(t0, stats + 1024, g2, be2, t1);

    // ---- head ----
    k_fc<<<NN * OUTE / 256, 256, 0, stream>>>(t1, Wfc, bfc, mask, adj, out);
}